// Round 1
// baseline (1445.380 us; speedup 1.0000x reference)
//
#include <hip/hip_runtime.h>

#define FFT_N 512
#define LOG2N 9

__device__ __forceinline__ float2 cmul(float2 a, float2 b) {
    return make_float2(a.x * b.x - a.y * b.y, a.x * b.y + a.y * b.x);
}

// Stockham radix-2 autosort FFT, 512 complex points in LDS, 256 threads
// (one butterfly per thread per stage). sign = -1 forward, +1 inverse
// (inverse is unscaled). Data starts in x; returns pointer to the buffer
// holding the result (after 9 stages this is the other buffer).
__device__ float2* fft512(float2* x, float2* y, int tid, float sign) {
    int n = FFT_N;
    int s = 1;
#pragma unroll
    for (int st = 0; st < LOG2N; ++st) {
        int m = n >> 1;
        int p = tid >> st;        // tid / s
        int q = tid & (s - 1);    // tid % s
        float2 a = x[q + s * p];
        float2 b = x[q + s * (p + m)];
        float ang = sign * 6.28318530717958647692f * (float)p / (float)n;
        float sn, cs;
        __sincosf(ang, &sn, &cs);
        float2 sum = make_float2(a.x + b.x, a.y + b.y);
        float2 dif = make_float2(a.x - b.x, a.y - b.y);
        // x and y are distinct buffers: no hazard between this stage's reads
        // and writes, so a single barrier after the writes suffices.
        y[q + s * (2 * p)]     = sum;
        y[q + s * (2 * p + 1)] = cmul(dif, make_float2(cs, sn));
        __syncthreads();
        float2* t = x; x = y; y = t;
        n = m;
        s <<= 1;
    }
    return x;
}

// Pass 1: forward FFT along W for every row of every (b,c) image.
__global__ __launch_bounds__(256) void fft_rows_fwd(const float* __restrict__ x,
                                                    float2* __restrict__ out) {
    __shared__ float2 b0[FFT_N];
    __shared__ float2 b1[FFT_N];
    const int t = threadIdx.x;
    const size_t row = blockIdx.x;
    const float* xr = x + row * FFT_N;
    b0[t]       = make_float2(xr[t], 0.f);
    b0[t + 256] = make_float2(xr[t + 256], 0.f);
    __syncthreads();
    float2* res = fft512(b0, b1, t, -1.f);
    float2* o = out + row * FFT_N;
    o[t]       = res[t];
    o[t + 256] = res[t + 256];
}

// Pass 2: per column w of each image: forward FFT over h, multiply by
// H[kh][w], inverse FFT over h (unscaled). In-place on the workspace.
__global__ __launch_bounds__(256) void fft_cols(float2* __restrict__ data,
                                                const float* __restrict__ Hr,
                                                const float* __restrict__ Hi) {
    __shared__ float2 b0[FFT_N];
    __shared__ float2 b1[FFT_N];
    const int t = threadIdx.x;
    const int col = blockIdx.x;
    const int w = col & (FFT_N - 1);
    const int img = col >> LOG2N;
    float2* base = data + (size_t)img * FFT_N * FFT_N + w;
    b0[t]       = base[(size_t)t * FFT_N];
    b0[t + 256] = base[(size_t)(t + 256) * FFT_N];
    __syncthreads();
    float2* res = fft512(b0, b1, t, -1.f);
    // Pointwise complex filter at (kh, w).
    {
        int kh = t;
        float2 h = make_float2(Hr[kh * FFT_N + w], Hi[kh * FFT_N + w]);
        res[kh] = cmul(res[kh], h);
        kh = t + 256;
        h = make_float2(Hr[kh * FFT_N + w], Hi[kh * FFT_N + w]);
        res[kh] = cmul(res[kh], h);
    }
    __syncthreads();
    float2* other = (res == b0) ? b1 : b0;
    float2* res2 = fft512(res, other, t, +1.f);
    base[(size_t)t * FFT_N]         = res2[t];
    base[(size_t)(t + 256) * FFT_N] = res2[t + 256];
}

// Pass 3: inverse FFT along W, keep real part, apply 1/(512*512).
__global__ __launch_bounds__(256) void fft_rows_inv(const float2* __restrict__ in,
                                                    float* __restrict__ out) {
    __shared__ float2 b0[FFT_N];
    __shared__ float2 b1[FFT_N];
    const int t = threadIdx.x;
    const size_t row = blockIdx.x;
    const float2* xr = in + row * FFT_N;
    b0[t]       = xr[t];
    b0[t + 256] = xr[t + 256];
    __syncthreads();
    float2* res = fft512(b0, b1, t, +1.f);
    const float scale = 1.0f / (512.f * 512.f);
    float* o = out + row * FFT_N;
    o[t]       = res[t].x * scale;
    o[t + 256] = res[t + 256].x * scale;
}

extern "C" void kernel_launch(void* const* d_in, const int* in_sizes, int n_in,
                              void* d_out, int out_size, void* d_ws, size_t ws_size,
                              hipStream_t stream) {
    const float* x  = (const float*)d_in[0];   // [8,16,512,512]
    const float* Hr = (const float*)d_in[1];   // [512,512]
    const float* Hi = (const float*)d_in[2];   // [512,512]
    float* out = (float*)d_out;

    float2* ws = (float2*)d_ws;                // 8*16*512*512 complex = 256 MiB

    const int n_rows = 8 * 16 * 512;           // 65536 row FFTs
    const int n_cols = 8 * 16 * 512;           // 65536 column FFTs

    fft_rows_fwd<<<n_rows, 256, 0, stream>>>(x, ws);
    fft_cols<<<n_cols, 256, 0, stream>>>(ws, Hr, Hi);
    fft_rows_inv<<<n_rows, 256, 0, stream>>>(ws, out);
}

// Round 2
// 750.490 us; speedup vs baseline: 1.9259x; 1.9259x over previous
//
#include <hip/hip_runtime.h>

#define FFT_N   512
#define CSTR    577              // padded per-FFT stride in float2 (max PADIDX=574, odd for conflict-free staging)
#define R_TILE  4                // rows per block in row passes
#define C_TILE  8                // columns per block in column pass (8 float2 = 64B = one cache line)

#define PADIDX(i) ((i) + ((i) >> 3))   // LDS swizzle: breaks pow2-stride bank conflicts in late stages

__device__ __forceinline__ float2 cmul(float2 a, float2 b) {
    return make_float2(a.x * b.x - a.y * b.y, a.x * b.y + a.y * b.x);
}

// In-place radix-2 DIF: natural-order input, bit-reversed-order output.
// 256 threads, one butterfly per thread per stage, NCOL FFTs per block.
// sign = -1 for forward transform. __syncthreads at end of every stage.
template <int NCOL>
__device__ __forceinline__ void fft512_dif(float2* __restrict__ buf, int t, float sign) {
#pragma unroll
    for (int st = 0; st < 9; ++st) {
        const int L = FFT_N >> st;      // current sub-transform length
        const int m = L >> 1;
        const int g = t >> (8 - st);    // t / m  (m = 2^(8-st))
        const int j = t & (m - 1);      // t % m
        const int i0 = g * L + j;
        const int i1 = i0 + m;
        const int a0 = PADIDX(i0), a1 = PADIDX(i1);
        float ang = sign * 6.28318530717958647692f * (float)j / (float)L;
        float sn, cs;
        __sincosf(ang, &sn, &cs);
        const float2 w = make_float2(cs, sn);
        float2 va[NCOL], vb[NCOL];
#pragma unroll
        for (int c = 0; c < NCOL; ++c) {
            va[c] = buf[c * CSTR + a0];
            vb[c] = buf[c * CSTR + a1];
        }
#pragma unroll
        for (int c = 0; c < NCOL; ++c) {
            buf[c * CSTR + a0] = make_float2(va[c].x + vb[c].x, va[c].y + vb[c].y);
            buf[c * CSTR + a1] = cmul(make_float2(va[c].x - vb[c].x, va[c].y - vb[c].y), w);
        }
        __syncthreads();
    }
}

// In-place radix-2 DIT: bit-reversed-order input, natural-order output.
// sign = +1 for (unscaled) inverse transform.
template <int NCOL>
__device__ __forceinline__ void fft512_dit(float2* __restrict__ buf, int t, float sign) {
#pragma unroll
    for (int st = 0; st < 9; ++st) {
        const int L = 2 << st;
        const int m = L >> 1;           // m = 2^st
        const int g = t >> st;          // t / m
        const int j = t & (m - 1);      // t % m
        const int i0 = g * L + j;
        const int i1 = i0 + m;
        const int a0 = PADIDX(i0), a1 = PADIDX(i1);
        float ang = sign * 6.28318530717958647692f * (float)j / (float)L;
        float sn, cs;
        __sincosf(ang, &sn, &cs);
        const float2 w = make_float2(cs, sn);
        float2 va[NCOL], vb[NCOL];
#pragma unroll
        for (int c = 0; c < NCOL; ++c) {
            va[c] = buf[c * CSTR + a0];
            vb[c] = cmul(buf[c * CSTR + a1], w);
        }
#pragma unroll
        for (int c = 0; c < NCOL; ++c) {
            buf[c * CSTR + a0] = make_float2(va[c].x + vb[c].x, va[c].y + vb[c].y);
            buf[c * CSTR + a1] = make_float2(va[c].x - vb[c].x, va[c].y - vb[c].y);
        }
        __syncthreads();
    }
}

// Pass 1: forward FFT along W, 4 rows per block. Output positions hold
// bit-reversed frequencies (consumed consistently downstream).
__global__ __launch_bounds__(256) void fft_rows_fwd(const float* __restrict__ x,
                                                    float2* __restrict__ out) {
    __shared__ float2 buf[R_TILE * CSTR];
    const int t = threadIdx.x;
    const size_t tile = blockIdx.x;                 // 16384 tiles of 4 rows
    const float* src = x + tile * (R_TILE * FFT_N);
#pragma unroll
    for (int k = 0; k < 8; ++k) {
        int f = t + k * 256;                        // 0..2047
        int r = f >> 9, i = f & 511;
        buf[r * CSTR + PADIDX(i)] = make_float2(src[f], 0.f);
    }
    __syncthreads();
    fft512_dif<R_TILE>(buf, t, -1.f);
    float2* dst = out + tile * (R_TILE * FFT_N);
#pragma unroll
    for (int k = 0; k < 8; ++k) {
        int f = t + k * 256;
        int r = f >> 9, i = f & 511;
        dst[f] = buf[r * CSTR + PADIDX(i)];
    }
}

// Pass 2: per image, 8 adjacent columns per block: forward FFT over h,
// pointwise filter (bit-reversed freq indexing), inverse FFT over h.
__global__ __launch_bounds__(256) void fft_cols(float2* __restrict__ data,
                                                const float* __restrict__ Hr,
                                                const float* __restrict__ Hi) {
    __shared__ float2 buf[C_TILE * CSTR];
    const int t = threadIdx.x;
    const int tile = blockIdx.x;                    // 128 imgs * 64 w-tiles
    const int img = tile >> 6;
    const int w0 = (tile & 63) * C_TILE;
    float2* base = data + (size_t)img * FFT_N * FFT_N + w0;

    // Stage 512 rows x 8 adjacent columns: 8 lanes cover one full 64B line.
#pragma unroll
    for (int k = 0; k < 16; ++k) {
        int h = (t >> 3) + k * 32;
        int c = t & 7;
        buf[c * CSTR + PADIDX(h)] = base[(size_t)h * FFT_N + c];
    }
    __syncthreads();

    fft512_dif<C_TILE>(buf, t, -1.f);

    // Pointwise filter: position q along h holds kh = bitrev9(q); column
    // position w0+c holds kw = bitrev9(w0+c) (from pass-1 DIF).
#pragma unroll
    for (int half = 0; half < 2; ++half) {
        int q = t + half * 256;
        int kh = (int)(__brev((unsigned)q) >> 23);
#pragma unroll
        for (int c = 0; c < C_TILE; ++c) {
            int kw = (int)(__brev((unsigned)(w0 + c)) >> 23);
            float2 hv = make_float2(Hr[kh * FFT_N + kw], Hi[kh * FFT_N + kw]);
            int a = c * CSTR + PADIDX(q);
            buf[a] = cmul(buf[a], hv);
        }
    }
    __syncthreads();

    fft512_dit<C_TILE>(buf, t, +1.f);

#pragma unroll
    for (int k = 0; k < 16; ++k) {
        int h = (t >> 3) + k * 32;
        int c = t & 7;
        base[(size_t)h * FFT_N + c] = buf[c * CSTR + PADIDX(h)];
    }
}

// Pass 3: inverse FFT along W (input bit-reversed, DIT -> natural order),
// keep real part, scale by 1/(512*512).
__global__ __launch_bounds__(256) void fft_rows_inv(const float2* __restrict__ in,
                                                    float* __restrict__ out) {
    __shared__ float2 buf[R_TILE * CSTR];
    const int t = threadIdx.x;
    const size_t tile = blockIdx.x;
    const float2* src = in + tile * (R_TILE * FFT_N);
#pragma unroll
    for (int k = 0; k < 8; ++k) {
        int f = t + k * 256;
        int r = f >> 9, i = f & 511;
        buf[r * CSTR + PADIDX(i)] = src[f];
    }
    __syncthreads();
    fft512_dit<R_TILE>(buf, t, +1.f);
    const float scale = 1.0f / (512.f * 512.f);
    float* dst = out + tile * (R_TILE * FFT_N);
#pragma unroll
    for (int k = 0; k < 8; ++k) {
        int f = t + k * 256;
        int r = f >> 9, i = f & 511;
        dst[f] = buf[r * CSTR + PADIDX(i)].x * scale;
    }
}

extern "C" void kernel_launch(void* const* d_in, const int* in_sizes, int n_in,
                              void* d_out, int out_size, void* d_ws, size_t ws_size,
                              hipStream_t stream) {
    const float* x  = (const float*)d_in[0];   // [8,16,512,512]
    const float* Hr = (const float*)d_in[1];   // [512,512]
    const float* Hi = (const float*)d_in[2];   // [512,512]
    float* out = (float*)d_out;
    float2* ws = (float2*)d_ws;                // 8*16*512*512 float2 = 256 MiB

    const int n_row_tiles = 8 * 16 * 512 / R_TILE;   // 16384
    const int n_col_tiles = 8 * 16 * (512 / C_TILE); // 8192

    fft_rows_fwd<<<n_row_tiles, 256, 0, stream>>>(x, ws);
    fft_cols<<<n_col_tiles, 256, 0, stream>>>(ws, Hr, Hi);
    fft_rows_inv<<<n_row_tiles, 256, 0, stream>>>(ws, out);
}

// Round 3
// 494.648 us; speedup vs baseline: 2.9220x; 1.5172x over previous
//
#include <hip/hip_runtime.h>

__device__ __forceinline__ float2 cmul(float2 a, float2 b) {
    return make_float2(a.x*b.x - a.y*b.y, a.x*b.y + a.y*b.x);
}
__device__ __forceinline__ float2 cadd(float2 a, float2 b){ return make_float2(a.x+b.x, a.y+b.y); }
__device__ __forceinline__ float2 csub(float2 a, float2 b){ return make_float2(a.x-b.x, a.y-b.y); }

// multiply by (0, SGN): forward SGN=-1, inverse SGN=+1
template<int SGN> __device__ __forceinline__ float2 mul_i(float2 a) {
    return (SGN > 0) ? make_float2(-a.y, a.x) : make_float2(a.y, -a.x);
}
// W8^1 = (r, SGN*r), r = sqrt(0.5)
template<int SGN> __device__ __forceinline__ float2 mul_w81(float2 a) {
    const float r = 0.70710678118654752440f;
    return (SGN > 0) ? make_float2(r*(a.x - a.y), r*(a.x + a.y))
                     : make_float2(r*(a.x + a.y), r*(a.y - a.x));
}
// W8^3 = (-r, SGN*r)
template<int SGN> __device__ __forceinline__ float2 mul_w83(float2 a) {
    const float r = 0.70710678118654752440f;
    return (SGN > 0) ? make_float2(-r*(a.x + a.y), r*(a.x - a.y))
                     : make_float2(r*(a.y - a.x), -r*(a.x + a.y));
}

// 8-point DFT in registers, natural-order output: out[q] = sum_k in[k] W8^{SGN*qk}
template<int SGN>
__device__ __forceinline__ void bfly8(float2 v[8]) {
    float2 s0 = cadd(v[0], v[4]), d0 = csub(v[0], v[4]);
    float2 s1 = cadd(v[1], v[5]), d1 = csub(v[1], v[5]);
    float2 s2 = cadd(v[2], v[6]), d2 = csub(v[2], v[6]);
    float2 s3 = cadd(v[3], v[7]), d3 = csub(v[3], v[7]);
    d1 = mul_w81<SGN>(d1);
    d2 = mul_i<SGN>(d2);
    d3 = mul_w83<SGN>(d3);
    float2 p0 = cadd(s0, s2), q0 = csub(s0, s2);
    float2 p1 = cadd(s1, s3), q1 = mul_i<SGN>(csub(s1, s3));
    float2 P0 = cadd(d0, d2), Q0 = csub(d0, d2);
    float2 P1 = cadd(d1, d3), Q1 = mul_i<SGN>(csub(d1, d3));
    v[0] = cadd(p0, p1);
    v[4] = csub(p0, p1);
    v[2] = cadd(q0, q1);
    v[6] = csub(q0, q1);
    v[1] = cadd(P0, P1);
    v[5] = csub(P0, P1);
    v[3] = cadd(Q0, Q1);
    v[7] = csub(Q0, Q1);
}

// v[q] *= W^{SGN*q}, W = cis(2*pi*frac)
template<int SGN>
__device__ __forceinline__ void twiddle7(float2 v[8], float frac) {
    const float ang = (SGN > 0 ? 6.2831853071795864769f : -6.2831853071795864769f) * frac;
    float sn, cs; __sincosf(ang, &sn, &cs);
    const float2 w1 = make_float2(cs, sn);
    float2 w = w1;
    v[1] = cmul(v[1], w);
#pragma unroll
    for (int q = 2; q < 8; ++q) { w = cmul(w, w1); v[q] = cmul(v[q], w); }
}

// Swizzles for the two LDS exchanges (both uniform 4 accesses/bank for b64):
//   f1(a) = a + 2*(a>>6)  (exchange stride-64 <-> stride-8 pattern)
//   f2(a) = a + (a>>3)    (exchange stride-8  <-> contiguous pattern)

// Forward 512-pt FFT, one wave, lane l (0..63), v preloaded with h = l+64k.
// Output: v[q] = spectrum value at position p = 8l+q (freq = octal-digit-rev(p)).
// S: per-wave scratch, >= 575 float2. Uses 2 block barriers.
__device__ __forceinline__ void fft512_fwd(float2 v[8], float2* S, int l) {
    const int g = l >> 3, j = l & 7;
    bfly8<-1>(v);
    twiddle7<-1>(v, (float)l * (1.0f/512.0f));
#pragma unroll
    for (int q = 0; q < 8; ++q) S[66*q + l] = v[q];          // f1(64q+l)
    __syncthreads();
#pragma unroll
    for (int k = 0; k < 8; ++k) v[k] = S[66*g + j + 8*k];    // f1(64g+j+8k)
    bfly8<-1>(v);
    twiddle7<-1>(v, (float)j * (1.0f/64.0f));
#pragma unroll
    for (int q = 0; q < 8; ++q) S[72*g + 9*q + j] = v[q];    // f2(64g+8q+j)
    __syncthreads();
#pragma unroll
    for (int k = 0; k < 8; ++k) v[k] = S[9*l + k];           // f2(8l+k)
    bfly8<-1>(v);
}

// Inverse (unscaled, x512): input v[q] = value at position 8l+q, output
// v[k] = natural-order sample at h = l+64k. Exact mirror of fft512_fwd.
__device__ __forceinline__ void fft512_inv(float2 v[8], float2* S, int l) {
    const int g = l >> 3, j = l & 7;
    bfly8<1>(v);
#pragma unroll
    for (int k = 0; k < 8; ++k) S[9*l + k] = v[k];
    __syncthreads();
#pragma unroll
    for (int q = 0; q < 8; ++q) v[q] = S[72*g + 9*q + j];
    twiddle7<1>(v, (float)j * (1.0f/64.0f));
    bfly8<1>(v);
#pragma unroll
    for (int k = 0; k < 8; ++k) S[66*g + j + 8*k] = v[k];
    __syncthreads();
#pragma unroll
    for (int q = 0; q < 8; ++q) v[q] = S[66*q + l];
    twiddle7<1>(v, (float)l * (1.0f/512.0f));
    bfly8<1>(v);
}

__device__ __forceinline__ int drev(int x) {   // reverse 3 octal digits of 9-bit x
    return ((x & 7) << 6) | (x & 56) | (x >> 6);
}

// Prologue: Hp[pw*512 + ph] = H[drev(ph)][drev(pw)] so pass-2 filter loads
// are contiguous. Hp lives in d_out (dead until pass 3 overwrites it fully).
__global__ __launch_bounds__(256) void permH(const float* __restrict__ Hr,
                                             const float* __restrict__ Hi,
                                             float2* __restrict__ Hp) {
    const int pw = blockIdx.x;
    const int kw = drev(pw);
    for (int ph = threadIdx.x; ph < 512; ph += 256) {
        const int kh = drev(ph);
        Hp[(pw << 9) + ph] = make_float2(Hr[(kh << 9) + kw], Hi[(kh << 9) + kw]);
    }
}

// Pass 1: forward FFT along W. 4 waves/block, one row per wave.
__global__ __launch_bounds__(256) void pass1_rows(const float* __restrict__ x,
                                                  float2* __restrict__ ws) {
    __shared__ float2 smem[4 * 577];
    const int t = threadIdx.x;
    const int l = t & 63, w = t >> 6;
    float2* S = smem + w * 577;
    const size_t row = (size_t)blockIdx.x * 4 + w;
    const float* src = x + row * 512;
    float2 v[8];
#pragma unroll
    for (int k = 0; k < 8; ++k) v[k] = make_float2(src[l + 64*k], 0.f);
    fft512_fwd(v, S, l);
    float4* dst = (float4*)(ws + row * 512 + 8*l);   // 64B contiguous per lane
#pragma unroll
    for (int q = 0; q < 4; ++q)
        dst[q] = make_float4(v[2*q].x, v[2*q].y, v[2*q+1].x, v[2*q+1].y);
}

// Pass 2: 8 adjacent columns per block (512 thr = 8 waves), one column per
// wave. Coop line-complete staging; FFT scratch aliases the staging buffer.
__global__ __launch_bounds__(512) void pass2_cols(float2* __restrict__ ws,
                                                  const float2* __restrict__ Hp) {
    __shared__ float2 smem[4616];      // interleaved staging 9*511+7 <= 4606; 8 scratches of 577
    const int t = threadIdx.x;
    const int l = t & 63, w = t >> 6;  // wave id == column-in-tile
    const int img = blockIdx.x >> 6;
    const int w0 = (blockIdx.x & 63) * 8;
    float2* base = ws + ((size_t)img << 18) + w0;

    {   // stage-in: 8 full 64B lines per wave-instruction
        const int c = t & 7, u = t >> 3;
#pragma unroll
        for (int k = 0; k < 8; ++k) {
            int h = u + 64*k;
            smem[9*h + c] = base[(size_t)h * 512 + c];
        }
    }
    __syncthreads();
    float2 v[8];
#pragma unroll
    for (int k = 0; k < 8; ++k) v[k] = smem[9*(l + 64*k) + w];
    __syncthreads();                   // staging dead; scratch may alias it
    float2* S = smem + w * 577;
    fft512_fwd(v, S, l);
    {   // filter: kh = drev(8l+q), kw = drev(w0+w) — pre-baked into Hp
        const float4* hp = (const float4*)(Hp + (((size_t)(w0 + w)) << 9) + 8*l);
#pragma unroll
        for (int q = 0; q < 4; ++q) {
            float4 h2 = hp[q];
            v[2*q]   = cmul(v[2*q],   make_float2(h2.x, h2.y));
            v[2*q+1] = cmul(v[2*q+1], make_float2(h2.z, h2.w));
        }
    }
    fft512_inv(v, S, l);
    __syncthreads();                   // all waves done with scratch
#pragma unroll
    for (int k = 0; k < 8; ++k) smem[9*(l + 64*k) + w] = v[k];
    __syncthreads();
    {   // stage-out, line-complete
        const int c = t & 7, u = t >> 3;
#pragma unroll
        for (int k = 0; k < 8; ++k) {
            int h = u + 64*k;
            base[(size_t)h * 512 + c] = smem[9*h + c];
        }
    }
}

// Pass 3: inverse FFT along W, real part, scale 1/512^2.
__global__ __launch_bounds__(256) void pass3_rows(const float2* __restrict__ ws,
                                                  float* __restrict__ out) {
    __shared__ float2 smem[4 * 577];
    const int t = threadIdx.x;
    const int l = t & 63, w = t >> 6;
    float2* S = smem + w * 577;
    const size_t row = (size_t)blockIdx.x * 4 + w;
    const float4* src = (const float4*)(ws + row * 512 + 8*l);
    float2 v[8];
#pragma unroll
    for (int q = 0; q < 4; ++q) {
        float4 p = src[q];
        v[2*q]   = make_float2(p.x, p.y);
        v[2*q+1] = make_float2(p.z, p.w);
    }
    fft512_inv(v, S, l);
    const float sc = 1.0f / (512.0f * 512.0f);
    float* dst = out + row * 512;
#pragma unroll
    for (int k = 0; k < 8; ++k) dst[l + 64*k] = v[k].x * sc;
}

extern "C" void kernel_launch(void* const* d_in, const int* in_sizes, int n_in,
                              void* d_out, int out_size, void* d_ws, size_t ws_size,
                              hipStream_t stream) {
    const float* x  = (const float*)d_in[0];   // [8,16,512,512]
    const float* Hr = (const float*)d_in[1];   // [512,512]
    const float* Hi = (const float*)d_in[2];   // [512,512]
    float* out = (float*)d_out;
    float2* ws = (float2*)d_ws;                // 256 MiB complex workspace
    float2* Hp = (float2*)d_out;               // 16 MiB of d_out reused as scratch;
                                               // pass 3 fully overwrites d_out after.

    permH<<<512, 256, 0, stream>>>(Hr, Hi, Hp);
    pass1_rows<<<16384, 256, 0, stream>>>(x, ws);
    pass2_cols<<<8192, 512, 0, stream>>>(ws, Hp);
    pass3_rows<<<16384, 256, 0, stream>>>(ws, out);
}